// Round 1
// baseline (250.359 us; speedup 1.0000x reference)
//
#include <hip/hip_runtime.h>

// RepformerLayer attention: nf=1, nloc=1024, nnei=128, ng2=nd=32, nh=4. f32 I/O.
// Transposed dataflow rewrite: compute q2^T (C-layout == 16x16x16 B-frag),
// S^T via 16x16x16 MFMAs (lane holds a full softmax ROW -> 2 shuffles, P is
// lane-local), value path T^T/oh^T via 16x16x16 with per-q scale applied
// post-MFMA (columns are q). ZERO LDS writes / fences / transposes in the
// main loop. G2H/G2L XOR-swizzled (col ^= (row&3)<<3, 16B granule) so b64
// A-frag reads are conflict-free; b128 reads unaffected. W2 frags re-read
// from read-only PQ staging per head to cap VGPRs. Heads inner, strips outer.

typedef __bf16 v8bf __attribute__((ext_vector_type(8)));
typedef float  v4f  __attribute__((ext_vector_type(4)));
typedef unsigned short u16x4 __attribute__((ext_vector_type(4)));
typedef short s16x4 __attribute__((ext_vector_type(4)));

__device__ __forceinline__ float b2f(unsigned short b) {
    union { unsigned u; float f; } x; x.u = ((unsigned)b) << 16; return x.f;
}
__device__ __forceinline__ unsigned short f2b(float f) {
    union { float f; unsigned u; } x; x.f = f;
    unsigned r = x.u + 0x7FFFu + ((x.u >> 16) & 1u);
    return (unsigned short)(r >> 16);
}
struct HL { unsigned short hi, lo; };
__device__ __forceinline__ HL splitbf(float f) {
    HL r; r.hi = f2b(f); r.lo = f2b(f - b2f(r.hi)); return r;
}
union W8 { unsigned short u[8]; v8bf v; };

#define MF(a,b,c) __builtin_amdgcn_mfma_f32_16x16x32_bf16((a),(b),(c),0,0,0)

#if __has_builtin(__builtin_amdgcn_mfma_f32_16x16x16bf16_1k)
__device__ __forceinline__ v4f MF16(s16x4 a, s16x4 b, v4f c) {
    return __builtin_amdgcn_mfma_f32_16x16x16bf16_1k(a, b, c, 0, 0, 0);
}
#else
// Exact emulation: zero-pad K16 frags into low half of each quad's K32 slots.
__device__ __forceinline__ v4f MF16(s16x4 a, s16x4 b, v4f c) {
    W8 A, B;
    #pragma unroll
    for (int j = 0; j < 4; j++) {
        A.u[j] = (unsigned short)a[j]; A.u[j + 4] = 0;
        B.u[j] = (unsigned short)b[j]; B.u[j + 4] = 0;
    }
    return MF(A.v, B.v, c);
}
#endif

// LDS offsets (u16 units)
#define G2H 0        // [128][32] g2 hi, col^=(row&3)<<3 swizzle
#define G2L 4096     // [128][32] g2 lo, same swizzle
#define G2T 8192     // [32][136] g2 hi transposed * es[k] (pad 136)
#define NQH 12544    // [4][32][32] NQ[c'][c] = M[c][c'] hi (M=WqWk^T)
#define NQL 16640
#define H2T 20736    // [4][128] bf16 * es[k], row 3 = zeros
#define PQ  21248    // [4][32][32] W2buf[o][c] per head (prologue staging, RO after)
#define SM_U16 25344 // 50688 B + 3072 smf = 53760 B

__global__ __launch_bounds__(256, 3) void repformer_kernel(
    const float* __restrict__ g2, const float* __restrict__ h2,
    const float* __restrict__ sw, const float* __restrict__ wqk,
    const float* __restrict__ wv, const float* __restrict__ wh,
    const float* __restrict__ bh, const float* __restrict__ weq,
    const int*   __restrict__ nmask, float* __restrict__ out)
{
    __shared__ __align__(16) unsigned short sm[SM_U16];
    __shared__ __align__(16) float smf[768];   // h2s[128][4] | sws[128] | es[128]
    float* h2s = smf;
    float* sws = smf + 512;
    float* es  = smf + 640;

    const int t    = threadIdx.x;
    const int i    = blockIdx.x;
    const int lane = t & 63;
    const int wv4  = t >> 6;
    const int quad = lane >> 4;
    const int n16  = lane & 15;
    const int h    = wv4;          // prologue fold: wave w -> head w

    // ---------------- stage per-loc inputs ----------------
    {
        const float4* src = (const float4*)(g2 + (size_t)i * 4096);
        #pragma unroll
        for (int j = 0; j < 4; j++) {
            int idx = j * 256 + t;
            float4 v = src[idx];
            u16x4 ph, pl;
            HL a0 = splitbf(v.x); ph[0] = a0.hi; pl[0] = a0.lo;
            HL a1 = splitbf(v.y); ph[1] = a1.hi; pl[1] = a1.lo;
            HL a2 = splitbf(v.z); ph[2] = a2.hi; pl[2] = a2.lo;
            HL a3 = splitbf(v.w); ph[3] = a3.hi; pl[3] = a3.lo;
            int k = idx >> 3, c0 = (idx & 7) * 4;
            int swz = k * 32 + (c0 ^ ((k & 3) << 3));
            *(u16x4*)(sm + G2H + swz) = ph;
            *(u16x4*)(sm + G2L + swz) = pl;
            sm[G2T + (c0 + 0) * 136 + k] = ph[0];   // transpose hi copy (unswizzled)
            sm[G2T + (c0 + 1) * 136 + k] = ph[1];
            sm[G2T + (c0 + 2) * 136 + k] = ph[2];
            sm[G2T + (c0 + 3) * 136 + k] = ph[3];
        }
    }
    for (int e = t; e < 384; e += 256) {
        float f = h2[(size_t)i * 384 + e];
        int k = e / 3, c = e - k * 3;
        h2s[k * 4 + c] = f;
        sm[H2T + c * 128 + k] = f2b(f);
    }
    if (t < 128) {
        sm[H2T + 384 + t] = 0;
        float s = sw[i * 128 + t];
        sws[t] = s;
        es[t]  = (nmask[i * 128 + t] != 0) ? s : 0.0f;
    }

    // ---------------- prologue weight folds: wave w folds head w ----------
    #pragma unroll
    for (int mt = 0; mt < 2; mt++) {
        W8 akh, akl, avh, avl;
        #pragma unroll
        for (int j = 0; j < 8; j++) {
            HL k2 = splitbf(wqk[(mt * 16 + n16) * 256 + (quad * 8 + j) * 8 + 4 + h]); // Wk[c][d]
            akh.u[j] = k2.hi; akl.u[j] = k2.lo;
            HL v2 = splitbf(wv[(mt * 16 + n16) * 128 + (quad * 8 + j) * 4 + h]);      // Wv[c][g]
            avh.u[j] = v2.hi; avl.u[j] = v2.lo;
        }
        #pragma unroll
        for (int nt = 0; nt < 2; nt++) {
            W8 bqh, bql, bhh, bhl;
            #pragma unroll
            for (int j = 0; j < 8; j++) {
                HL q2w = splitbf(wqk[(nt * 16 + n16) * 256 + (quad * 8 + j) * 8 + h]); // Wq[c'][d]
                bqh.u[j] = q2w.hi; bql.u[j] = q2w.lo;
                HL h2w = splitbf(wh[((quad * 8 + j) * 4 + h) * 32 + nt * 16 + n16]);   // Wh[g][o]
                bhh.u[j] = h2w.hi; bhl.u[j] = h2w.lo;
            }
            v4f z = {0.f, 0.f, 0.f, 0.f};
            v4f c1 = MF(akh.v, bqh.v, MF(akl.v, bqh.v, MF(akh.v, bql.v, z)));
            #pragma unroll
            for (int r = 0; r < 4; r++) {    // C[m=c][n=c'] -> NQ[c][c'] = M[c'][c]... stored as before
                HL s1 = splitbf(c1[r]);
                int addr = h * 1024 + (mt * 16 + quad * 4 + r) * 32 + nt * 16 + n16;
                sm[NQH + addr] = s1.hi; sm[NQL + addr] = s1.lo;
            }
            v4f c2 = MF(avh.v, bhh.v, MF(avl.v, bhh.v, MF(avh.v, bhl.v, z)));
            #pragma unroll
            for (int r = 0; r < 4; r++)      // C[m=c][n=o] -> W2buf[o][c]
                sm[PQ + h * 1024 + (nt * 16 + n16) * 32 + mt * 16 + quad * 4 + r] = f2b(c2[r]);
        }
    }
    __syncthreads();

    // ---- fold es[k] into G2T/H2T columns ----
    {
        int kcol = t & 127;
        int cb = (t >> 7) * 16;
        float ek = es[kcol];
        #pragma unroll
        for (int c = 0; c < 16; c++) {
            int idx = G2T + (cb + c) * 136 + kcol;
            sm[idx] = f2b(b2f(sm[idx]) * ek);
        }
        if (t < 128) {
            #pragma unroll
            for (int c = 0; c < 3; c++) {
                int idx = H2T + c * 128 + t;
                sm[idx] = f2b(b2f(sm[idx]) * es[t]);
            }
        }
    }
    __syncthreads();   // all LDS is READ-ONLY from here to the end

    const int hr = (n16 < 3) ? n16 : 3;
    float weqf[4];
    #pragma unroll
    for (int hh = 0; hh < 4; hh++) weqf[hh] = weq[hh];
    float* outg = out;
    float* outh = out + 4194304;   // 1024*128*32
    const float bias0 = bh[n16];
    const float bias1 = bh[16 + n16];
    const int sk = (n16 & 3) << 3;                       // G2H/G2L swizzle key
    const unsigned short* g2t0 = sm + G2T + n16 * 136;
    const unsigned short* g2t1 = sm + G2T + (16 + n16) * 136;
    const unsigned short* h2tp = sm + H2T + hr * 128;

    // =================== strips OUTER, heads INNER ===================
    #pragma unroll
    for (int sl = 0; sl < 2; sl++) {
        const int s = 2 * wv4 + sl;
        const int q = s * 16 + n16;                      // this lane's q-row
        const int goff = q * 32 + ((quad * 8) ^ sk);
        const v8bf gfh = *(const v8bf*)(sm + G2H + goff);
        const v8bf gfl = *(const v8bf*)(sm + G2L + goff);
        const float swq  = sws[q];
        const float mq   = (es[q] != 0.0f) ? 1.0f : 0.0f;
        const float swq20 = 20.0f * swq;
        const float kq    = 0.17677669529663687f * swq;  // swq / sqrt(32)
        const float hq0 = h2s[q * 4 + 0] * kq;
        const float hq1 = h2s[q * 4 + 1] * kq;
        const float hq2 = h2s[q * 4 + 2] * kq;
        float htcw[8][4];                                // htc * swq, kn = kt*16+quad*4+r
        #pragma unroll
        for (int kt = 0; kt < 8; kt++)
            #pragma unroll
            for (int r = 0; r < 4; r++) {
                const v4f hk = *(const v4f*)(h2s + (kt * 16 + quad * 4 + r) * 4);
                htcw[kt][r] = fmaf(hq2, hk[2], fmaf(hq1, hk[1], hq0 * hk[0]));
            }
        v4f og0 = {0.f, 0.f, 0.f, 0.f}, og1 = og0, ohacc = og0;

        #pragma unroll
        for (int hd = 0; hd < 4; hd++) {
            const v4f vz = {0.f, 0.f, 0.f, 0.f};
            // ---- q2^T tiles: C[c'][q] = sum_c M[c][c'] g2[q][c], 3-term dbl-bf16
            s16x4 qbh0, qbl0, qbh1, qbl1;
            {
                const unsigned short* nq = sm + NQH + hd * 1024;
                const unsigned short* nl = sm + NQL + hd * 1024;
                const v8bf nh0 = *(const v8bf*)(nq + n16 * 32 + quad * 8);
                const v8bf nl0 = *(const v8bf*)(nl + n16 * 32 + quad * 8);
                const v8bf nh1 = *(const v8bf*)(nq + (16 + n16) * 32 + quad * 8);
                const v8bf nl1 = *(const v8bf*)(nl + (16 + n16) * 32 + quad * 8);
                v4f c0t = MF(nh0, gfl, MF(nl0, gfh, MF(nh0, gfh, vz)));
                v4f c1t = MF(nh1, gfl, MF(nl1, gfh, MF(nh1, gfh, vz)));
                #pragma unroll
                for (int r = 0; r < 4; r++) {
                    HL a0 = splitbf(c0t[r]); qbh0[r] = (short)a0.hi; qbl0[r] = (short)a0.lo;
                    HL a1 = splitbf(c1t[r]); qbh1[r] = (short)a1.hi; qbl1[r] = (short)a1.lo;
                }
            }
            // ---- per 16-kn tile: S^T, softmax, lane-local P, value MFMAs ----
            v4f T0 = vz, T1 = vz, ohl = vz;
            float sum = 0.f;
            #pragma unroll
            for (int kt = 0; kt < 8; kt++) {
                const unsigned short* gr = sm + G2H + (kt * 16 + n16) * 32;
                const unsigned short* glo = sm + G2L + (kt * 16 + n16) * 32;
                const int o0 = (quad * 4) ^ sk;
                const int o1 = (16 + quad * 4) ^ sk;
                const s16x4 ah0 = *(const s16x4*)(gr + o0);
                const s16x4 al0 = *(const s16x4*)(glo + o0);
                const s16x4 ah1 = *(const s16x4*)(gr + o1);
                const s16x4 al1 = *(const s16x4*)(glo + o1);
                v4f st = MF16(ah0, qbl0, MF16(al0, qbh0, MF16(ah0, qbh0, vz)));
                st     = MF16(ah1, qbl1, MF16(al1, qbh1, MF16(ah1, qbh1, st)));
                // st[r] = S[q][kn], kn = kt*16+quad*4+r
                const v4f swk4 = *(const v4f*)(sws + kt * 16 + quad * 4);
                s16x4 pk;
                #pragma unroll
                for (int r = 0; r < 4; r++) {
                    float l = fmaf(fmaf(st[r], htcw[kt][r], swq20), swk4[r], -20.0f);
                    float p = __expf(l);
                    sum += p;
                    pk[r] = (short)f2b(p * htcw[kt][r]);   // P*htc*swq (scale applied later)
                }
                T0  = MF16(*(const s16x4*)(g2t0 + kt * 16 + quad * 4), pk, T0);
                T1  = MF16(*(const s16x4*)(g2t1 + kt * 16 + quad * 4), pk, T1);
                ohl = MF16(*(const s16x4*)(h2tp + kt * 16 + quad * 4), pk, ohl);
            }
            sum += __shfl_xor(sum, 16, 64);
            sum += __shfl_xor(sum, 32, 64);
            // mask_q * sqrt(32)/sqrt(3) / denom  (swq already folded into P)
            const float scale = mq * 3.2659863237109f * __builtin_amdgcn_rcpf(sum);
            s16x4 ta0, ta1;
            #pragma unroll
            for (int r = 0; r < 4; r++) {
                ta0[r] = (short)f2b(scale * T0[r]);
                ta1[r] = (short)f2b(scale * T1[r]);
            }
            const unsigned short* wp = sm + PQ + hd * 1024;
            const s16x4 w00 = *(const s16x4*)(wp + n16 * 32 + quad * 4);
            const s16x4 w01 = *(const s16x4*)(wp + n16 * 32 + 16 + quad * 4);
            const s16x4 w10 = *(const s16x4*)(wp + (16 + n16) * 32 + quad * 4);
            const s16x4 w11 = *(const s16x4*)(wp + (16 + n16) * 32 + 16 + quad * 4);
            og0 = MF16(ta1, w01, MF16(ta0, w00, og0));
            og1 = MF16(ta1, w11, MF16(ta0, w10, og1));
            const float ws = weqf[hd] * scale;
            #pragma unroll
            for (int r = 0; r < 4; r++) ohacc[r] = fmaf(ws, ohl[r], ohacc[r]);
        }

        // ---- strip epilogue (f32 out): og C-layout rows = q, cols = o ----
        const int qg = i * 128 + s * 16;
        #pragma unroll
        for (int r = 0; r < 4; r++) {
            outg[(size_t)(qg + quad * 4 + r) * 32 + n16]      = og0[r] + bias0;
            outg[(size_t)(qg + quad * 4 + r) * 32 + 16 + n16] = og1[r] + bias1;
        }
        if (quad == 0) {
            #pragma unroll
            for (int r = 0; r < 3; r++)
                outh[(size_t)(qg + n16) * 3 + r] = ohacc[r];
        }
    }
}

extern "C" void kernel_launch(void* const* d_in, const int* in_sizes, int n_in,
                              void* d_out, int out_size, void* d_ws, size_t ws_size,
                              hipStream_t stream) {
    const float* g2  = (const float*)d_in[0];
    const float* h2  = (const float*)d_in[1];
    const float* sw  = (const float*)d_in[2];
    const float* wqk = (const float*)d_in[3];
    const float* wv  = (const float*)d_in[4];
    const float* wh  = (const float*)d_in[5];
    const float* bh  = (const float*)d_in[6];
    const float* weq = (const float*)d_in[7];
    const int*   nm  = (const int*)d_in[8];
    int nloc = in_sizes[0] / (128 * 32);   // 1024
    repformer_kernel<<<nloc, 256, 0, stream>>>(g2, h2, sw, wqk, wv, wh, bh, weq, nm, (float*)d_out);
}

// Round 2
// 209.033 us; speedup vs baseline: 1.1977x; 1.1977x over previous
//
#include <hip/hip_runtime.h>

// RepformerLayer attention: nf=1, nloc=1024, nnei=128, ng2=nd=32, nh=4. f32 I/O.
// Transposed dataflow, K32-only: q2^T C-layout feeds S^T MFMAs directly because
// NQ rows are stored PERMUTED (row' = ((x>>2)&1)*16 + ((x>>3)<<2) + (x&3)) so the
// two C-tiles concat into a v8bf K32 B-frag (k-slot quad*8+j). Same permutation
// on G2T rows makes T^T C-tiles concat into the og A-frag; S^T A-rows are read
// permuted so lane-local P rows land in the value-MFMA B-frag k-slots. Lane
// holds a full softmax ROW (2 shuffles for the denom); P/T never touch LDS.
// ZERO LDS writes / fences / transposes in the main loop; all operands v8bf.
// G2H/G2L/NQ/W2buf XOR-swizzled (col ^= (row&3)<<3) -> conflict-free b128 reads.
// exp2-domain softmax: log2e folded into htcwE, ln2 folded into final scale.

typedef __bf16 v8bf __attribute__((ext_vector_type(8)));
typedef float  v4f  __attribute__((ext_vector_type(4)));
typedef unsigned short u16x4 __attribute__((ext_vector_type(4)));

__device__ __forceinline__ float b2f(unsigned short b) {
    union { unsigned u; float f; } x; x.u = ((unsigned)b) << 16; return x.f;
}
__device__ __forceinline__ unsigned short f2b(float f) {
    union { float f; unsigned u; } x; x.f = f;
    unsigned r = x.u + 0x7FFFu + ((x.u >> 16) & 1u);
    return (unsigned short)(r >> 16);
}
struct HL { unsigned short hi, lo; };
__device__ __forceinline__ HL splitbf(float f) {
    HL r; r.hi = f2b(f); r.lo = f2b(f - b2f(r.hi)); return r;
}
union W8 { unsigned short u[8]; v8bf v; };

#define MF(a,b,c) __builtin_amdgcn_mfma_f32_16x16x32_bf16((a),(b),(c),0,0,0)

#if __has_builtin(__builtin_amdgcn_exp2f)
#define EXP2(x) __builtin_amdgcn_exp2f(x)
#else
#define EXP2(x) __expf((x) * 0.6931471805599453f)
#endif

// LDS offsets (u16 units)
#define G2H 0        // [128][32] g2 hi, col ^= (row&3)<<3
#define G2L 4096     // [128][32] g2 lo, same swizzle
#define G2T 8192     // [32][136] g2^T * es[k], rows PERMUTED, hi only
#define NQH 12544    // [4][32][32] M-cols, rows PERMUTED, col-swizzled
#define NQL 16640
#define H2T 20736    // [4][136] h2^T * es[k], row 3 zeros
#define PQ  21280    // [4][32][32] W2fold[o][c], col-swizzled
#define SM_U16 25376 // 50752 B + 3072 smf = 53824 B (<= 54613 for 3 blocks/CU)

__global__ __launch_bounds__(256, 3) void repformer_kernel(
    const float* __restrict__ g2, const float* __restrict__ h2,
    const float* __restrict__ sw, const float* __restrict__ wqk,
    const float* __restrict__ wv, const float* __restrict__ wh,
    const float* __restrict__ bh, const float* __restrict__ weq,
    const int*   __restrict__ nmask, float* __restrict__ out)
{
    __shared__ __align__(16) unsigned short sm[SM_U16];
    __shared__ __align__(16) float smf[768];   // h2s[128][4] | sws[128] | es[128]
    float* h2s = smf;
    float* sws = smf + 512;
    float* es  = smf + 640;

    const int t    = threadIdx.x;
    const int i    = blockIdx.x;
    const int lane = t & 63;
    const int wv4  = t >> 6;
    const int quad = lane >> 4;
    const int n16  = lane & 15;
    const int h    = wv4;          // prologue fold: wave w -> head w

    // ---------------- stage per-loc inputs ----------------
    {
        const float4* src = (const float4*)(g2 + (size_t)i * 4096);
        #pragma unroll
        for (int j = 0; j < 4; j++) {
            int idx = j * 256 + t;
            float4 v = src[idx];
            u16x4 ph, pl;
            HL a0 = splitbf(v.x); ph[0] = a0.hi; pl[0] = a0.lo;
            HL a1 = splitbf(v.y); ph[1] = a1.hi; pl[1] = a1.lo;
            HL a2 = splitbf(v.z); ph[2] = a2.hi; pl[2] = a2.lo;
            HL a3 = splitbf(v.w); ph[3] = a3.hi; pl[3] = a3.lo;
            int k = idx >> 3, c0 = (idx & 7) * 4;
            int swz = k * 32 + (c0 ^ ((k & 3) << 3));
            *(u16x4*)(sm + G2H + swz) = ph;
            *(u16x4*)(sm + G2L + swz) = pl;
            #pragma unroll
            for (int cc = 0; cc < 4; cc++) {       // transpose, PERMUTED rows
                int c  = c0 + cc;
                int rp = ((c >> 2) & 1) * 16 + ((c >> 3) << 2) + (c & 3);
                sm[G2T + rp * 136 + k] = ph[cc];
            }
        }
    }
    for (int e = t; e < 384; e += 256) {
        float f = h2[(size_t)i * 384 + e];
        int k = e / 3, c = e - k * 3;
        h2s[k * 4 + c] = f;
        sm[H2T + c * 136 + k] = f2b(f);
    }
    if (t < 128) {
        sm[H2T + 3 * 136 + t] = 0;
        float s = sw[i * 128 + t];
        sws[t] = s;
        es[t]  = (nmask[i * 128 + t] != 0) ? s : 0.0f;
    }

    // ---------------- prologue weight folds: wave w folds head w ----------
    #pragma unroll
    for (int mt = 0; mt < 2; mt++) {
        W8 akh, akl, avh, avl;
        #pragma unroll
        for (int j = 0; j < 8; j++) {
            HL k2 = splitbf(wqk[(mt * 16 + n16) * 256 + (quad * 8 + j) * 8 + 4 + h]); // Wk[c][d]
            akh.u[j] = k2.hi; akl.u[j] = k2.lo;
            HL v2 = splitbf(wv[(mt * 16 + n16) * 128 + (quad * 8 + j) * 4 + h]);      // Wv[c][g]
            avh.u[j] = v2.hi; avl.u[j] = v2.lo;
        }
        #pragma unroll
        for (int nt = 0; nt < 2; nt++) {
            W8 bqh, bql, bhh, bhl;
            #pragma unroll
            for (int j = 0; j < 8; j++) {
                HL q2w = splitbf(wqk[(nt * 16 + n16) * 256 + (quad * 8 + j) * 8 + h]); // Wq[c'][d]
                bqh.u[j] = q2w.hi; bql.u[j] = q2w.lo;
                HL h2w = splitbf(wh[((quad * 8 + j) * 4 + h) * 32 + nt * 16 + n16]);   // Wh[g][o]
                bhh.u[j] = h2w.hi; bhl.u[j] = h2w.lo;
            }
            v4f z = {0.f, 0.f, 0.f, 0.f};
            // c1[r] = M[nt*16+n16][x], x = mt*16+quad*4+r  (M = Wq Wk^T)
            v4f c1 = MF(akh.v, bqh.v, MF(akl.v, bqh.v, MF(akh.v, bql.v, z)));
            #pragma unroll
            for (int r = 0; r < 4; r++) {
                HL s1 = splitbf(c1[r]);
                int x    = mt * 16 + quad * 4 + r;                       // M column
                int rowp = ((x >> 2) & 1) * 16 + ((x >> 3) << 2) + (x & 3);
                int addr = h * 1024 + rowp * 32 + ((nt * 16 + n16) ^ ((rowp & 3) << 3));
                sm[NQH + addr] = s1.hi; sm[NQL + addr] = s1.lo;
            }
            // c2[r] = W2fold[c = mt*16+quad*4+r][o = nt*16+n16]
            v4f c2 = MF(avh.v, bhh.v, MF(avl.v, bhh.v, MF(avh.v, bhl.v, z)));
            #pragma unroll
            for (int r = 0; r < 4; r++) {
                int o  = nt * 16 + n16;
                int cw = mt * 16 + quad * 4 + r;
                sm[PQ + h * 1024 + o * 32 + (cw ^ ((o & 3) << 3))] = f2b(c2[r]);
            }
        }
    }
    __syncthreads();

    // ---- fold es[k] into G2T/H2T columns ----
    {
        int kcol = t & 127;
        int cb = (t >> 7) * 16;
        float ek = es[kcol];
        #pragma unroll
        for (int c = 0; c < 16; c++) {
            int idx = G2T + (cb + c) * 136 + kcol;
            sm[idx] = f2b(b2f(sm[idx]) * ek);
        }
        if (t < 128) {
            #pragma unroll
            for (int c = 0; c < 3; c++) {
                int idx = H2T + c * 136 + t;
                sm[idx] = f2b(b2f(sm[idx]) * es[t]);
            }
        }
    }
    __syncthreads();   // all LDS is READ-ONLY from here to the end

    const int hr = (n16 < 3) ? n16 : 3;
    float weqf[4];
    #pragma unroll
    for (int hh = 0; hh < 4; hh++) weqf[hh] = weq[hh];
    float* outg = out;
    float* outh = out + 4194304;   // 1024*128*32
    const float bias0 = bh[n16];
    const float bias1 = bh[16 + n16];
    const int skx = (n16 & 3) << 3;                      // XOR-swizzle key
    const int qo  = (quad * 8) ^ skx;                    // swizzled col base
    const int rowbase = ((n16 >> 2) << 3) + (n16 & 3);   // S^T A-row permutation
    const unsigned short* g2t0 = sm + G2T + n16 * 136;
    const unsigned short* g2t1 = sm + G2T + (16 + n16) * 136;
    const unsigned short* h2tp = sm + H2T + hr * 136;

    // =================== strips OUTER, heads INNER ===================
    #pragma unroll
    for (int sl = 0; sl < 2; sl++) {
        const int s = 2 * wv4 + sl;
        const int q = s * 16 + n16;                      // this lane's q-row
        const v8bf gfh = *(const v8bf*)(sm + G2H + q * 32 + qo);
        const v8bf gfl = *(const v8bf*)(sm + G2L + q * 32 + qo);
        const float swq   = sws[q];
        const float mq    = (es[q] != 0.0f) ? 1.0f : 0.0f;
        const float swq20E = swq * 28.853900817779268f;  // 20*swq*log2e
        const float kq     = 0.17677669529663687f * 1.4426950408889634f * swq;
        const float hq0 = h2s[q * 4 + 0] * kq;
        const float hq1 = h2s[q * 4 + 1] * kq;
        const float hq2 = h2s[q * 4 + 2] * kq;
        float htcwE[8][4];                               // ht*swq/sqrt(32)*log2e
        #pragma unroll
        for (int t8 = 0; t8 < 8; t8++)
            #pragma unroll
            for (int r = 0; r < 4; r++) {
                const int kn = (t8 >> 1) * 32 + quad * 8 + (t8 & 1) * 4 + r;
                const v4f hk = *(const v4f*)(h2s + kn * 4);
                htcwE[t8][r] = fmaf(hq2, hk[2], fmaf(hq1, hk[1], hq0 * hk[0]));
            }
        v4f og0 = {0.f, 0.f, 0.f, 0.f}, og1 = og0, ohacc = og0;

        #pragma unroll
        for (int hd = 0; hd < 4; hd++) {
            const v4f vz = {0.f, 0.f, 0.f, 0.f};
            // ---- q2^T: 2 C-tiles, permuted NQ rows -> K32 B-frag on concat
            const unsigned short* nqh = sm + NQH + hd * 1024;
            const unsigned short* nql = sm + NQL + hd * 1024;
            const v8bf nh0 = *(const v8bf*)(nqh + n16 * 32 + qo);
            const v8bf nl0 = *(const v8bf*)(nql + n16 * 32 + qo);
            const v8bf nh1 = *(const v8bf*)(nqh + (16 + n16) * 32 + qo);
            const v8bf nl1 = *(const v8bf*)(nql + (16 + n16) * 32 + qo);
            v4f c0t = MF(nh0, gfl, MF(nl0, gfh, MF(nh0, gfh, vz)));
            v4f c1t = MF(nh1, gfl, MF(nl1, gfh, MF(nh1, gfh, vz)));
            v8bf qh, ql;
            #pragma unroll
            for (int j = 0; j < 4; j++) {
                float f0 = c0t[j]; __bf16 h0 = (__bf16)f0;
                qh[j] = h0; ql[j] = (__bf16)(f0 - (float)h0);
                float f1 = c1t[j]; __bf16 h1 = (__bf16)f1;
                qh[j + 4] = h1; ql[j + 4] = (__bf16)(f1 - (float)h1);
            }
            // ---- per 32-kn chunk: 2 S^T tiles -> softmax -> P-frag -> values
            v4f T0 = vz, T1 = vz, ohl = vz;
            float sum = 0.f;
            #pragma unroll
            for (int ks = 0; ks < 4; ks++) {
                v8bf pv;
                #pragma unroll
                for (int half = 0; half < 2; half++) {
                    const int row = ks * 32 + rowbase + half * 4;   // permuted A-row
                    const int ga = row * 32 + qo;
                    const v8bf ah = *(const v8bf*)(sm + G2H + ga);
                    const v8bf al = *(const v8bf*)(sm + G2L + ga);
                    const v4f st = MF(ah, ql, MF(al, qh, MF(ah, qh, vz)));
                    const int t8 = ks * 2 + half;
                    const v4f swk4 = *(const v4f*)(sws + ks * 32 + quad * 8 + half * 4);
                    #pragma unroll
                    for (int r = 0; r < 4; r++) {
                        float l2 = fmaf(fmaf(st[r], htcwE[t8][r], swq20E), swk4[r],
                                        -28.853900817779268f);
                        float p = EXP2(l2);
                        sum += p;
                        pv[half * 4 + r] = (__bf16)(p * htcwE[t8][r]);
                    }
                }
                T0  = MF(*(const v8bf*)(g2t0 + ks * 32 + quad * 8), pv, T0);
                T1  = MF(*(const v8bf*)(g2t1 + ks * 32 + quad * 8), pv, T1);
                ohl = MF(*(const v8bf*)(h2tp + ks * 32 + quad * 8), pv, ohl);
            }
            sum += __shfl_xor(sum, 16, 64);
            sum += __shfl_xor(sum, 32, 64);
            // mq * sqrt(32)/sqrt(3) * ln2 / denom  (ln2 un-does log2e in htcwE)
            const float scale = mq * 2.2638092f * __builtin_amdgcn_rcpf(sum);
            v8bf ta;
            #pragma unroll
            for (int j = 0; j < 4; j++) {
                ta[j]     = (__bf16)(scale * T0[j]);
                ta[j + 4] = (__bf16)(scale * T1[j]);
            }
            const unsigned short* wp = sm + PQ + hd * 1024;
            og0 = MF(ta, *(const v8bf*)(wp + n16 * 32 + qo), og0);
            og1 = MF(ta, *(const v8bf*)(wp + (16 + n16) * 32 + qo), og1);
            const float ws = weqf[hd] * scale;
            #pragma unroll
            for (int r = 0; r < 4; r++) ohacc[r] = fmaf(ws, ohl[r], ohacc[r]);
        }

        // ---- strip epilogue (f32 out): og rows = q (quad*4+r), cols = o ----
        const int qg = i * 128 + s * 16;
        #pragma unroll
        for (int r = 0; r < 4; r++) {
            outg[(size_t)(qg + quad * 4 + r) * 32 + n16]      = og0[r] + bias0;
            outg[(size_t)(qg + quad * 4 + r) * 32 + 16 + n16] = og1[r] + bias1;
        }
        if (quad == 0) {
            #pragma unroll
            for (int r = 0; r < 3; r++)
                outh[(size_t)(qg + n16) * 3 + r] = ohacc[r];
        }
    }
}

extern "C" void kernel_launch(void* const* d_in, const int* in_sizes, int n_in,
                              void* d_out, int out_size, void* d_ws, size_t ws_size,
                              hipStream_t stream) {
    const float* g2  = (const float*)d_in[0];
    const float* h2  = (const float*)d_in[1];
    const float* sw  = (const float*)d_in[2];
    const float* wqk = (const float*)d_in[3];
    const float* wv  = (const float*)d_in[4];
    const float* wh  = (const float*)d_in[5];
    const float* bh  = (const float*)d_in[6];
    const float* weq = (const float*)d_in[7];
    const int*   nm  = (const int*)d_in[8];
    int nloc = in_sizes[0] / (128 * 32);   // 1024
    repformer_kernel<<<nloc, 256, 0, stream>>>(g2, h2, sw, wqk, wv, wh, bh, weq, nm, (float*)d_out);
}